// Round 3
// baseline (110.538 us; speedup 1.0000x reference)
//
#include <hip/hip_runtime.h>
#include <hip/hip_fp16.h>

// Problem constants (from reference)
#define SPP   16
#define SH    256
#define SW    256
#define HI    1024
#define WI    1024
#define CH    3
#define BATCH 4

// 16-B load with only 8-B guaranteed alignment (gfx950 HW needs only dword
// alignment for dwordx4; worst case the compiler splits into 2x dwordx2).
struct __attribute__((packed, aligned(8))) U4 { uint4 v; };

// tanh via v_exp_f32; |x| <= ~1.2 here, error ~1e-6 (threshold is 1.7e-2).
__device__ __forceinline__ float fast_tanh(float x) {
    const float t = __expf(2.0f * x);
    return (t - 1.0f) * __builtin_amdgcn_rcpf(t + 1.0f);
}

// -------- Pass 1: NCHW f32 -> NHWC4 fp16 repack (streaming, coalesced) -----
__global__ __launch_bounds__(256) void repack_kernel(
    const float* __restrict__ img, __half* __restrict__ dst)
{
    const int tid = blockIdx.x * 256 + threadIdx.x;     // 0 .. 4*2^20-1
    const int b   = tid >> 20;
    const int pix = tid & (HI * WI - 1);
    const float* p = img + (size_t)b * (CH * HI * WI) + pix;
    union { __half2 h2[2]; uint2 u; } u;
    u.h2[0] = __floats2half2_rn(p[0], p[HI * WI]);
    u.h2[1] = __floats2half2_rn(p[2 * HI * WI], 0.0f);
    *(uint2*)(dst + ((size_t)tid << 2)) = u.u;          // 8 B/lane, coalesced
}

// -------- Pass 2: main kernel on NHWC4 fp16 --------------------------------
// grid = 4096 blocks x 256. Logical block L (XCD slab swizzle):
//   b = L>>10, sy = (L>>2)&255, xg = L&3  (64-px x-group)
// wave: pxl = lane&15 (pixel), q = lane>>4 (spp quarter, 4 spp each)
// reduce quarters via __shfl_xor 16,32. XCD slab = 4 MB fp16 -> L2-resident.
__global__ __launch_bounds__(256) void foveated_nhwc(
    const __half* __restrict__ img4,
    const float* __restrict__ t_ptr,
    const float* __restrict__ jitter,
    float* __restrict__ out)
{
    const int L  = (blockIdx.x & 7) * 512 + (blockIdx.x >> 3);
    const int b  = L >> 10;
    const int sy = (L >> 2) & (SH - 1);
    const int xg = L & 3;

    const int th   = threadIdx.x;
    const int lane = th & 63;
    const int pxl  = lane & 15;
    const int q    = lane >> 4;          // spp quarter
    const int wv   = th >> 6;            // wave in block
    const int sx   = xg * 64 + wv * 16 + pxl;

    const float step  = 2.0f / 256.0f;
    const float tt    = t_ptr[0];
    const float inv_s = __builtin_amdgcn_rcpf(fast_tanh(tt));

    const float px = -1.0f + sx * step;
    const float py = -1.0f + sy * step;

    float acc0 = 0.0f, acc1 = 0.0f, acc2 = 0.0f, dsum = 0.0f;

    const __half* __restrict__ base = img4 + (size_t)b * (HI * WI * 4);
    const float2* __restrict__ jit2 = (const float2*)jitter;
    const int jbase = sy * SW + sx;

    #pragma unroll
    for (int k = 0; k < SPP / 4; ++k) {
        const int sp = q * 4 + k;
        const float2 j = jit2[sp * (SH * SW) + jbase];
        const float posx = px + j.x * step;
        const float posy = py + j.y * step;

        const float thx = fast_tanh(tt * posx);
        const float thy = fast_tanh(tt * posy);
        const float ddx = tt * (1.0f - thx * thx) * inv_s;
        const float ddy = tt * (1.0f - thy * thy) * inv_s;
        const float det = ddx * ddy;

        float gx = (thx * inv_s + 1.0f) * (WI * 0.5f) - 0.5f;
        float gy = (thy * inv_s + 1.0f) * (HI * 0.5f) - 0.5f;
        gx = fminf(fmaxf(gx, 0.0f), (float)(WI - 1));
        gy = fminf(fmaxf(gy, 0.0f), (float)(HI - 1));

        const int xb = min((int)gx, WI - 2);
        const int yb = min((int)gy, HI - 2);
        const float fx = gx - (float)xb;   // reaches 1.0 at right border
        const float fy = gy - (float)yb;   // == reference clamp algebra

        const float w00 = (1.0f - fx) * (1.0f - fy) * det;
        const float w01 = fx * (1.0f - fy) * det;
        const float w10 = (1.0f - fx) * fy * det;
        const float w11 = fx * fy * det;
        dsum += det;

        const __half* r0 = base + (((size_t)yb * WI + xb) << 2);
        const uint4 a = ((const U4*)r0)->v;              // row yb:  px xb, xb+1
        const uint4 c = ((const U4*)(r0 + (WI << 2)))->v; // row yb+1

        const __half2* ha = (const __half2*)&a;
        const __half2* hc = (const __half2*)&c;
        const float2 a0 = __half22float2(ha[0]);  // px0: c0,c1
        const float2 a1 = __half22float2(ha[1]);  // px0: c2,pad
        const float2 a2 = __half22float2(ha[2]);  // px1: c0,c1
        const float2 a3 = __half22float2(ha[3]);  // px1: c2,pad
        const float2 c0 = __half22float2(hc[0]);
        const float2 c1 = __half22float2(hc[1]);
        const float2 c2 = __half22float2(hc[2]);
        const float2 c3 = __half22float2(hc[3]);

        acc0 += w00 * a0.x + w01 * a2.x + w10 * c0.x + w11 * c2.x;
        acc1 += w00 * a0.y + w01 * a2.y + w10 * c0.y + w11 * c2.y;
        acc2 += w00 * a1.x + w01 * a3.x + w10 * c1.x + w11 * c3.x;
    }

    // Sum the 4 spp quarters (lanes with equal lane&15).
    acc0 += __shfl_xor(acc0, 16); acc0 += __shfl_xor(acc0, 32);
    acc1 += __shfl_xor(acc1, 16); acc1 += __shfl_xor(acc1, 32);
    acc2 += __shfl_xor(acc2, 16); acc2 += __shfl_xor(acc2, 32);
    dsum += __shfl_xor(dsum, 16); dsum += __shfl_xor(dsum, 32);

    if (q == 0) {
        const float inv_d = 1.0f / dsum;
        const int pix = sy * SW + sx;
        const size_t ob = (size_t)b * CH * (SH * SW) + pix;
        out[ob]                 = acc0 * inv_d;
        out[ob + (SH * SW)]     = acc1 * inv_d;
        out[ob + 2 * (SH * SW)] = acc2 * inv_d;
    }
}

// -------- Fallback (R1 kernel, used only if ws_size too small) -------------
__global__ __launch_bounds__(256) void foveated_kernel(
    const float* __restrict__ img,
    const float* __restrict__ t_ptr,
    const float* __restrict__ jitter,
    float* __restrict__ out)
{
    const int L  = (blockIdx.x & 7) * 256 + (blockIdx.x >> 3);
    const int b  = L >> 9;
    const int sy = (L >> 1) & (SH - 1);
    const int xh = L & 1;

    const int th   = threadIdx.x;
    const int lane = th & 31;
    const int half = (th >> 5) & 1;
    const int grp  = th >> 6;
    const int sx   = xh * 128 + grp * 32 + lane;

    const float step  = 2.0f / 256.0f;
    const float tt    = t_ptr[0];
    const float inv_s = 1.0f / tanhf(tt);

    const float px = -1.0f + sx * step;
    const float py = -1.0f + sy * step;

    float acc0 = 0.0f, acc1 = 0.0f, acc2 = 0.0f, dsum = 0.0f;

    const size_t plane = (size_t)HI * WI;
    const float* __restrict__ p0 = img + (size_t)(b * CH) * plane;
    const float* __restrict__ p1 = p0 + plane;
    const float* __restrict__ p2 = p1 + plane;

    const float2* __restrict__ jit2 = (const float2*)jitter;
    const int jbase = sy * SW + sx;

    #pragma unroll 4
    for (int k = 0; k < SPP / 2; ++k) {
        const int sp = half * (SPP / 2) + k;
        const float2 j = jit2[sp * (SH * SW) + jbase];
        const float posx = px + j.x * step;
        const float posy = py + j.y * step;

        const float thx = tanhf(tt * posx);
        const float thy = tanhf(tt * posy);
        const float ddx = tt * (1.0f - thx * thx) * inv_s;
        const float ddy = tt * (1.0f - thy * thy) * inv_s;
        const float det = ddx * ddy;

        float gx = (thx * inv_s + 1.0f) * (WI * 0.5f) - 0.5f;
        float gy = (thy * inv_s + 1.0f) * (HI * 0.5f) - 0.5f;
        gx = fminf(fmaxf(gx, 0.0f), (float)(WI - 1));
        gy = fminf(fmaxf(gy, 0.0f), (float)(HI - 1));

        const int xb = min((int)gx, WI - 2);
        const int yb = min((int)gy, HI - 2);
        const float fx = gx - (float)xb;
        const float fy = gy - (float)yb;

        const float w00 = (1.0f - fx) * (1.0f - fy) * det;
        const float w01 = fx * (1.0f - fy) * det;
        const float w10 = (1.0f - fx) * fy * det;
        const float w11 = fx * fy * det;
        dsum += det;

        const int i0 = yb * WI + xb;
        const int i1 = i0 + WI;
        { const float2 a = *(const float2*)(p0 + i0), c = *(const float2*)(p0 + i1);
          acc0 += a.x * w00 + a.y * w01 + c.x * w10 + c.y * w11; }
        { const float2 a = *(const float2*)(p1 + i0), c = *(const float2*)(p1 + i1);
          acc1 += a.x * w00 + a.y * w01 + c.x * w10 + c.y * w11; }
        { const float2 a = *(const float2*)(p2 + i0), c = *(const float2*)(p2 + i1);
          acc2 += a.x * w00 + a.y * w01 + c.x * w10 + c.y * w11; }
    }

    acc0 += __shfl_xor(acc0, 32);
    acc1 += __shfl_xor(acc1, 32);
    acc2 += __shfl_xor(acc2, 32);
    dsum += __shfl_xor(dsum, 32);

    if (half == 0) {
        const float inv_d = 1.0f / dsum;
        const int pix = sy * SW + sx;
        const size_t obase = (size_t)b * CH * (SH * SW) + pix;
        out[obase]                 = acc0 * inv_d;
        out[obase + (SH * SW)]     = acc1 * inv_d;
        out[obase + 2 * (SH * SW)] = acc2 * inv_d;
    }
}

extern "C" void kernel_launch(void* const* d_in, const int* in_sizes, int n_in,
                              void* d_out, int out_size, void* d_ws, size_t ws_size,
                              hipStream_t stream) {
    const float* img    = (const float*)d_in[0];
    const float* t      = (const float*)d_in[1];
    const float* jitter = (const float*)d_in[2];
    float* out          = (float*)d_out;

    const size_t need = (size_t)BATCH * HI * WI * 4 * sizeof(__half); // 32 MB
    if (ws_size >= need) {
        __half* img4 = (__half*)d_ws;
        hipLaunchKernelGGL(repack_kernel, dim3(BATCH * HI * WI / 256), dim3(256),
                           0, stream, img, img4);
        hipLaunchKernelGGL(foveated_nhwc, dim3(4096), dim3(256), 0, stream,
                           img4, t, jitter, out);
    } else {
        hipLaunchKernelGGL(foveated_kernel, dim3(2048), dim3(256), 0, stream,
                           img, t, jitter, out);
    }
}

// Round 4
// 108.787 us; speedup vs baseline: 1.0161x; 1.0161x over previous
//
#include <hip/hip_runtime.h>
#include <hip/hip_fp16.h>

// Problem constants (from reference)
#define SPP   16
#define SH    256
#define SW    256
#define HI    1024
#define WI    1024
#define CH    3
#define BATCH 4

#define TS    16    // sensor tile = 16x16 px per block (256 threads, 1 px/thread)
#define MAXD  88    // max bbox rows/cols at t=1: 84 px span +2 bilinear +2 safety

// tanh via v_exp_f32; |arg| <= ~1.2 here, abs error ~1e-6 (threshold 1.7e-2).
__device__ __forceinline__ float fast_tanh(float x) {
    const float e = __expf(2.0f * x);
    return (e - 1.0f) * __builtin_amdgcn_rcpf(e + 1.0f);
}

// Single kernel: per-block, stage the warped image bbox of a 16x16 sensor
// tile into LDS as fp16 NHWC4 (8 B/px), then each thread bilinearly samples
// its pixel's 16 jittered positions from LDS.
//
// Border algebra: xb = min(floor(gx), W-2), fx = gx - xb (reaches 1.0 at the
// border) — identical to the reference's clamp.
__global__ __launch_bounds__(256) void foveated_tile(
    const float* __restrict__ img,
    const float* __restrict__ t_ptr,
    const float* __restrict__ jitter,
    float* __restrict__ out)
{
    __shared__ uint2 lds[MAXD * MAXD];   // 61952 B

    // XCD slab swizzle: each XCD gets 128 contiguous logical blocks.
    const int bid  = blockIdx.x;
    const int L    = (bid & 7) * 128 + (bid >> 3);
    const int b    = L >> 8;
    const int trow = (L >> 4) & 15;
    const int tcol = L & 15;
    const int sx0  = tcol * TS;
    const int sy0  = trow * TS;

    const float step  = 2.0f / 256.0f;
    const float tt    = t_ptr[0];
    const float inv_s = __builtin_amdgcn_rcpf(fast_tanh(tt));

    // Uniform bbox of the tile's warped footprint (warp is monotone/separable).
    auto gmap = [&](float p) {
        float g = (fast_tanh(tt * p) * inv_s + 1.0f) * 512.0f - 0.5f;
        return fminf(fmaxf(g, 0.0f), 1023.0f);
    };
    const float pxmin = -1.0f + sx0 * step, pxmax = pxmin + TS * step;
    const float pymin = -1.0f + sy0 * step, pymax = pymin + TS * step;
    const int x_lo = max((int)gmap(pxmin) - 1, 0);
    const int x_hi = min((int)gmap(pxmax) + 2, WI - 1);
    const int y_lo = max((int)gmap(pymin) - 1, 0);
    const int y_hi = min((int)gmap(pymax) + 2, HI - 1);
    const int ncols = x_hi - x_lo + 1;
    const int nrows = y_hi - y_lo + 1;
    const bool fits = (ncols <= MAXD) && (nrows <= MAXD);  // always true at t=1

    const size_t plane = (size_t)HI * WI;
    const float* __restrict__ p0 = img + (size_t)(b * CH) * plane;
    const float* __restrict__ p1 = p0 + plane;
    const float* __restrict__ p2 = p1 + plane;

    const int th = threadIdx.x;
    const int sx = sx0 + (th & 15);
    const int sy = sy0 + (th >> 4);

    const float px = -1.0f + sx * step;
    const float py = -1.0f + sy * step;

    float acc0 = 0.0f, acc1 = 0.0f, acc2 = 0.0f, dsum = 0.0f;

    const float2* __restrict__ jit2 = (const float2*)jitter;
    const int jbase = sy * SW + sx;

    if (fits) {
        // ---- Stage bbox -> LDS (fp16 NHWC4), coalesced global reads ----
        const int npix = nrows * ncols;
        const unsigned mdiv = (1u << 22) / (unsigned)ncols + 1u;  // i<7744: exact
        for (int i = th; i < npix; i += 256) {
            const int r = (int)(((unsigned)i * mdiv) >> 22);
            const int c = i - r * ncols;
            const int g = (y_lo + r) * WI + (x_lo + c);
            union { __half2 h[2]; uint2 u; } v;
            v.h[0] = __floats2half2_rn(p0[g], p1[g]);
            v.h[1] = __floats2half2_rn(p2[g], 0.0f);
            lds[r * MAXD + c] = v.u;
        }
        __syncthreads();

        // ---- Sample 16 spp from LDS ----
        #pragma unroll 4
        for (int sp = 0; sp < SPP; ++sp) {
            const float2 j = jit2[sp * (SH * SW) + jbase];
            const float posx = px + j.x * step;
            const float posy = py + j.y * step;

            const float thx = fast_tanh(tt * posx);
            const float thy = fast_tanh(tt * posy);
            const float ddx = tt * (1.0f - thx * thx) * inv_s;
            const float ddy = tt * (1.0f - thy * thy) * inv_s;
            const float det = ddx * ddy;

            float gx = (thx * inv_s + 1.0f) * 512.0f - 0.5f;
            float gy = (thy * inv_s + 1.0f) * 512.0f - 0.5f;
            gx = fminf(fmaxf(gx, 0.0f), (float)(WI - 1));
            gy = fminf(fmaxf(gy, 0.0f), (float)(HI - 1));

            const int xb = min((int)gx, WI - 2);
            const int yb = min((int)gy, HI - 2);
            const float fx = gx - (float)xb;
            const float fy = gy - (float)yb;

            const float w00 = (1.0f - fx) * (1.0f - fy) * det;
            const float w01 = fx * (1.0f - fy) * det;
            const float w10 = (1.0f - fx) * fy * det;
            const float w11 = fx * fy * det;
            dsum += det;

            const int lidx = (yb - y_lo) * MAXD + (xb - x_lo);
            const uint2 q00 = lds[lidx];
            const uint2 q01 = lds[lidx + 1];
            const uint2 q10 = lds[lidx + MAXD];
            const uint2 q11 = lds[lidx + MAXD + 1];

            const float2 a00 = __half22float2(*(const __half2*)&q00.x);
            const float2 b00 = __half22float2(*(const __half2*)&q00.y);
            const float2 a01 = __half22float2(*(const __half2*)&q01.x);
            const float2 b01 = __half22float2(*(const __half2*)&q01.y);
            const float2 a10 = __half22float2(*(const __half2*)&q10.x);
            const float2 b10 = __half22float2(*(const __half2*)&q10.y);
            const float2 a11 = __half22float2(*(const __half2*)&q11.x);
            const float2 b11 = __half22float2(*(const __half2*)&q11.y);

            acc0 += w00 * a00.x + w01 * a01.x + w10 * a10.x + w11 * a11.x;
            acc1 += w00 * a00.y + w01 * a01.y + w10 * a10.y + w11 * a11.y;
            acc2 += w00 * b00.x + w01 * b01.x + w10 * b10.x + w11 * b11.x;
        }
    } else {
        // ---- Fallback: direct global gathers (never taken at t=1) ----
        #pragma unroll 4
        for (int sp = 0; sp < SPP; ++sp) {
            const float2 j = jit2[sp * (SH * SW) + jbase];
            const float posx = px + j.x * step;
            const float posy = py + j.y * step;

            const float thx = fast_tanh(tt * posx);
            const float thy = fast_tanh(tt * posy);
            const float ddx = tt * (1.0f - thx * thx) * inv_s;
            const float ddy = tt * (1.0f - thy * thy) * inv_s;
            const float det = ddx * ddy;

            float gx = (thx * inv_s + 1.0f) * 512.0f - 0.5f;
            float gy = (thy * inv_s + 1.0f) * 512.0f - 0.5f;
            gx = fminf(fmaxf(gx, 0.0f), (float)(WI - 1));
            gy = fminf(fmaxf(gy, 0.0f), (float)(HI - 1));

            const int xb = min((int)gx, WI - 2);
            const int yb = min((int)gy, HI - 2);
            const float fx = gx - (float)xb;
            const float fy = gy - (float)yb;

            const float w00 = (1.0f - fx) * (1.0f - fy) * det;
            const float w01 = fx * (1.0f - fy) * det;
            const float w10 = (1.0f - fx) * fy * det;
            const float w11 = fx * fy * det;
            dsum += det;

            const int i0 = yb * WI + xb;
            const int i1 = i0 + WI;
            { const float2 a = *(const float2*)(p0 + i0), c = *(const float2*)(p0 + i1);
              acc0 += a.x * w00 + a.y * w01 + c.x * w10 + c.y * w11; }
            { const float2 a = *(const float2*)(p1 + i0), c = *(const float2*)(p1 + i1);
              acc1 += a.x * w00 + a.y * w01 + c.x * w10 + c.y * w11; }
            { const float2 a = *(const float2*)(p2 + i0), c = *(const float2*)(p2 + i1);
              acc2 += a.x * w00 + a.y * w01 + c.x * w10 + c.y * w11; }
        }
    }

    const float inv_d = 1.0f / dsum;
    const int pix = sy * SW + sx;
    const size_t ob = (size_t)b * CH * (SH * SW) + pix;
    out[ob]                 = acc0 * inv_d;
    out[ob + (SH * SW)]     = acc1 * inv_d;
    out[ob + 2 * (SH * SW)] = acc2 * inv_d;
}

extern "C" void kernel_launch(void* const* d_in, const int* in_sizes, int n_in,
                              void* d_out, int out_size, void* d_ws, size_t ws_size,
                              hipStream_t stream) {
    const float* img    = (const float*)d_in[0];
    const float* t      = (const float*)d_in[1];
    const float* jitter = (const float*)d_in[2];
    float* out          = (float*)d_out;

    // 4 batches x 16x16 tiles = 1024 blocks, 256 threads (1 sensor px each)
    hipLaunchKernelGGL(foveated_tile, dim3(1024), dim3(256), 0, stream,
                       img, t, jitter, out);
}